// Round 7
// baseline (153.846 us; speedup 1.0000x reference)
//
#include <hip/hip_runtime.h>
#include <math.h>
#include <stdint.h>

#define NG 8
#define GS 2048
#define DM 512
#define NE 64
#define CAP 32
#define NROWS (NG * GS)                       // 16384 total rows (g,s)
#define COMBINE_ELEMS (33554432ull)           // 8*2048*64*32

#define ZERO_BLOCKS 2048
#define GATE_BLOCKS 256                       // 64 rows per block, 4 waves
#define N4 16777216                           // 268435456 B / 16

typedef float f32x4 __attribute__((ext_vector_type(4)));
typedef double f64x4 __attribute__((ext_vector_type(4)));

// ---------------------------------------------------------------------------
// JAX Threefry-2x32 (partitionable path).  [verified: rounds 1,3,4,5]
// ---------------------------------------------------------------------------
__device__ __forceinline__ void threefry2x32(uint32_t k0, uint32_t k1,
                                             uint32_t x0, uint32_t x1,
                                             uint32_t& o0, uint32_t& o1) {
  uint32_t ks[3] = {k0, k1, k0 ^ k1 ^ 0x1BD11BDAu};
  x0 += ks[0];
  x1 += ks[1];
  const uint32_t rot[2][4] = {{13u, 15u, 26u, 6u}, {17u, 29u, 16u, 24u}};
#pragma unroll
  for (int i = 0; i < 5; ++i) {
#pragma unroll
    for (int j = 0; j < 4; ++j) {
      uint32_t r = rot[i & 1][j];
      x0 += x1;
      x1 = (x1 << r) | (x1 >> (32u - r));
      x1 ^= x0;
    }
    x0 += ks[(i + 1) % 3];
    x1 += ks[(i + 2) % 3] + (uint32_t)(i + 1);
  }
  o0 = x0;
  o1 = x1;
}

// XLA ErfInv (f32), Giles polynomial — constants bit-match xla math.cc.
__device__ __forceinline__ float erfinv_xla(float x) {
  float w = -log1pf(-x * x);
  float p;
  if (w < 5.0f) {
    w = w - 2.5f;
    p = 2.81022636e-08f;
    p = __fmaf_rn(p, w, 3.43273939e-07f);
    p = __fmaf_rn(p, w, -3.5233877e-06f);
    p = __fmaf_rn(p, w, -4.39150654e-06f);
    p = __fmaf_rn(p, w, 0.00021858087f);
    p = __fmaf_rn(p, w, -0.00125372503f);
    p = __fmaf_rn(p, w, -0.00417768164f);
    p = __fmaf_rn(p, w, 0.246640727f);
    p = __fmaf_rn(p, w, 1.50140941f);
  } else {
    w = sqrtf(w) - 3.0f;
    p = -0.000200214257f;
    p = __fmaf_rn(p, w, 0.000100950558f);
    p = __fmaf_rn(p, w, 0.00134934322f);
    p = __fmaf_rn(p, w, -0.00367342844f);
    p = __fmaf_rn(p, w, 0.00573950773f);
    p = __fmaf_rn(p, w, -0.0076224613f);
    p = __fmaf_rn(p, w, 0.00943887047f);
    p = __fmaf_rn(p, w, 1.00167406f);
    p = __fmaf_rn(p, w, 2.83297682f);
  }
  return p * x;
}

__device__ __forceinline__ float jax_normal(uint32_t idx) {
  uint32_t o0, o1;
  threefry2x32(0u, 42u, 0u, idx, o0, o1);
  uint32_t bits = o0 ^ o1;
  float f = __uint_as_float((bits >> 9) | 0x3f800000u) - 1.0f;  // [0,1)
  const float lo = __uint_as_float(0xBF7FFFFFu);                // -0.99999994
  float v = fmaxf(lo, f * 2.0f + lo);
  return __uint_as_float(0x3FB504F3u) * erfinv_xla(v);  // sqrt(2)_f32 * erfinv
}

// ---------------------------------------------------------------------------
// Fused kernel: 2304 blocks = 256 gate (bid%9==0) + 2048 zero.
// Gate block: 4 waves; each wave one 16-row x 64-expert tile via
// v_mfma_f64_16x16x4_f64.  The acc-register -> row mapping is DISCOVERED at
// runtime with a marker MFMA (A = row label, B = 0.25), so the kernel is
// correct under either candidate D layout (round-6 lesson).
// LDS = exactly 128 KiB (proven-launchable size); x staged XOR-swizzled.
// ---------------------------------------------------------------------------
__global__ __launch_bounds__(256) void fused_kernel(
    const float* __restrict__ x,    // (NROWS, 512)
    const float* __restrict__ Wt,   // (512, 64)
    float* __restrict__ gatesT,     // (NG*NE, GS)
    f32x4* __restrict__ outv) {     // output as f32x4[N4]
  __shared__ float xs[64 * 512];    // 131072 B
  const int bid = blockIdx.x;
  const int role = bid % 9;

  if (role != 0) {
    // ---- zero block ----
    const int zid = (bid / 9) * 8 + (role - 1);   // 0..ZERO_BLOCKS-1
    const f32x4 z = {0.f, 0.f, 0.f, 0.f};
    for (int i = zid * 256 + threadIdx.x; i < N4; i += ZERO_BLOCKS * 256)
      __builtin_nontemporal_store(z, &outv[i]);
    return;
  }

  // ---- gate block ----
  const int gid = bid / 9;            // 0..255
  const int tid = threadIdx.x;
  const int l = tid & 63;             // lane
  const int w = tid >> 6;             // wave 0..3
  const int row0b = gid * 64;         // block's first row

  // stage 64 rows of x, XOR-swizzled: word (r,c) lives at xs[r*512 + (c ^ ((r&7)<<2))]
  for (int i = tid; i < 64 * 128; i += 256) {
    const int r = i >> 7;
    const int c4 = (i & 127) << 2;                 // word offset of the f32x4
    *(f32x4*)&xs[(r << 9) + (c4 ^ ((r & 7) << 2))] =
        *(const f32x4*)&x[(size_t)(row0b + r) * DM + c4];
  }
  __syncthreads();

  const int row0 = row0b + w * 16;    // wave's first row
  float* xw = xs + (w << 13);         // wave's private 16-row slice (16*512)

  const int i15 = l & 15;             // A row / B-C col position
  const int k4 = l >> 4;              // k-slot within K=4
  const int sw = (i15 & 7) << 2;      // read-side swizzle for this lane's row

  // --- runtime probe: which x-row does acc[*][r] hold? ---
  // A = row label (placed exactly like the x loads), B = 0.25 (k-sum = 1).
  f64x4 dr = {0., 0., 0., 0.};
  dr = __builtin_amdgcn_mfma_f64_16x16x4f64((double)i15, 0.25, dr, 0, 0, 0);
  int perm[4];
#pragma unroll
  for (int r = 0; r < 4; ++r) perm[r] = ((int)(dr[r] + 0.5)) & 15;

  // K-loop: 128 steps of K=4; acc[t] = 16x16 tile for experts 16t..16t+15
  f64x4 acc[4] = {{0., 0., 0., 0.}, {0., 0., 0., 0.},
                  {0., 0., 0., 0.}, {0., 0., 0., 0.}};
#pragma unroll 4
  for (int kk = 0; kk < 128; ++kk) {
    const double a = (double)xw[(i15 << 9) + ((kk << 2) ^ sw) + k4];
    const float* wrow = Wt + ((kk << 2) + k4) * NE;   // B[k=k4][col]
#pragma unroll
    for (int t = 0; t < 4; ++t) {
      const double b = (double)wrow[16 * t + i15];
      acc[t] = __builtin_amdgcn_mfma_f64_16x16x4f64(a, b, acc[t], 0, 0, 0);
    }
  }

  // noise + fp64 softmax. acc[t][r] = logits[row = row0+perm[r]][e = 16t+i15].
  // For fixed r the row is uniform across the 16-lane k4-group, so the
  // 16-lane shfl_xor reduce (offsets 1,2,4,8) spans exactly that row's
  // 64 experts (16 lanes x 4 t-regs).
  float gatef[4][4];  // [t][r]
#pragma unroll
  for (int r = 0; r < 4; ++r) {
    const int row = row0 + perm[r];
    double v[4];
    double m = -1.0e300;
#pragma unroll
    for (int t = 0; t < 4; ++t) {
      const float logit = (float)acc[t][r];
      const float noised =
          logit + 0.015625f * jax_normal((uint32_t)(row * NE + 16 * t + i15));
      v[t] = (double)noised;
      m = fmax(m, v[t]);
    }
#pragma unroll
    for (int off = 1; off < 16; off <<= 1) m = fmax(m, __shfl_xor(m, off, 64));
    double s = 0.0;
#pragma unroll
    for (int t = 0; t < 4; ++t) {
      v[t] = exp(v[t] - m);
      s += v[t];
    }
#pragma unroll
    for (int off = 1; off < 16; off <<= 1) s += __shfl_xor(s, off, 64);
#pragma unroll
    for (int t = 0; t < 4; ++t) gatef[t][r] = (float)(v[t] / s);
  }

  // per-wave LDS transpose (reuses the wave's own x slice; x is dead).
  // tb[e][sl] with stride 20 words; sl = perm[r] (true s-offset).
  float* tb = xw;
#pragma unroll
  for (int t = 0; t < 4; ++t)
#pragma unroll
    for (int r = 0; r < 4; ++r)
      tb[(16 * t + i15) * 20 + perm[r]] = gatef[t][r];

  const int g = row0 >> 11;           // group
  const int s0 = row0 & (GS - 1);     // first s of this wave's 16
  float* drow = gatesT + ((size_t)(g * NE + l)) * GS + s0;  // lane l -> expert l
#pragma unroll
  for (int c = 0; c < 4; ++c)
    *(f32x4*)&drow[4 * c] = *(const f32x4*)&tb[l * 20 + 4 * c];
}

// ---------------------------------------------------------------------------
// Topk: one WAVE per (group, expert); 8 coalesced f32x4 loads/lane; top-32
// via per-lane scan + shfl_xor butterfly (max value, min s on ties).
// [verified: rounds 4,5]
// ---------------------------------------------------------------------------
__global__ __launch_bounds__(64) void topk_kernel(
    const float* __restrict__ gatesT,  // (NG*NE, GS)
    float* __restrict__ out) {         // combine ++ dispatch
  const int ge = blockIdx.x;  // == g*64 + e
  const int g = ge >> 6;
  const int e = ge & 63;
  const int lane = threadIdx.x;

  const float* base = gatesT + (size_t)ge * GS;
  float v[32];
#pragma unroll
  for (int k = 0; k < 8; ++k) {
    const f32x4 t = *(const f32x4*)(base + k * 256 + lane * 4);
#pragma unroll
    for (int i = 0; i < 4; ++i) v[k * 4 + i] = t[i];
  }

  float my_v = 0.0f;
  int my_s = 0;

  for (int c = 0; c < CAP; ++c) {
    float bv = -1.0f;  // gates are strictly positive
    int bj = 0;
#pragma unroll
    for (int j = 0; j < 32; ++j) {
      const bool better = v[j] > bv;
      bv = better ? v[j] : bv;
      bj = better ? j : bj;
    }
    int bs = (bj >> 2) * 256 + lane * 4 + (bj & 3);
#pragma unroll
    for (int off = 1; off < 64; off <<= 1) {
      const float ov = __shfl_xor(bv, off, 64);
      const int os = __shfl_xor(bs, off, 64);
      if (ov > bv || (ov == bv && os < bs)) { bv = ov; bs = os; }
    }
    const bool owner = (lane == ((bs >> 2) & 63));
    const int jj = ((bs >> 8) << 2) | (bs & 3);
#pragma unroll
    for (int j = 0; j < 32; ++j) v[j] = (owner && j == jj) ? -1.0f : v[j];
    if (lane == c) { my_v = bv; my_s = bs; }
  }

  float* combine = out;                   // (G,S,E,C)
  float* dispatch = out + COMBINE_ELEMS;  // (G,E,C,S)
  if (lane < CAP) {
    combine[(((size_t)(g * GS + my_s)) * NE + e) * CAP + lane] = my_v;
    dispatch[(((size_t)(g * NE + e)) * CAP + lane) * GS + my_s] = 1.0f;
  }
}

extern "C" void kernel_launch(void* const* d_in, const int* in_sizes, int n_in,
                              void* d_out, int out_size, void* d_ws,
                              size_t ws_size, hipStream_t stream) {
  (void)in_sizes; (void)n_in; (void)ws_size; (void)out_size;
  const float* x = (const float*)d_in[0];   // (8,2048,512) f32
  const float* Wt = (const float*)d_in[1];  // (512,64) f32
  float* out = (float*)d_out;
  float* gatesT = (float*)d_ws;             // (512, 2048) f32 = 4 MB scratch

  fused_kernel<<<GATE_BLOCKS + ZERO_BLOCKS, 256, 0, stream>>>(
      x, Wt, gatesT, (f32x4*)out);
  topk_kernel<<<NG * NE, 64, 0, stream>>>(gatesT, out);
}